// Round 4
// baseline (2460.995 us; speedup 1.0000x reference)
//
#include <hip/hip_runtime.h>
#include <hip/hip_fp16.h>
#include <math.h>

#define HH 56
#define WW 56
#define HWPX 3136        // 56*56
#define CC 448
#define NBANK 100
#define KIM 20
#define OUTHW 224
#define CCH 32           // channels per chunk in kwin (fp16 LDS)

__device__ __forceinline__ float dot4(float4 a, float4 b) {
  return a.x*b.x + a.y*b.y + a.z*b.z + a.w*b.w;
}

__device__ __forceinline__ unsigned pack2h(float a, float b) {
  __half2 h;
  h.x = __float2half_rn(a);
  h.y = __float2half_rn(b);
  return *reinterpret_cast<unsigned*>(&h);
}

// ---------------- Kernel A: transpose (B,C,H,W) -> (B,HW,C) fp32+fp16, e2 ----
__global__ void ktrans(const float* __restrict__ emb, float* __restrict__ eT,
                       __half* __restrict__ eTh, float* __restrict__ e2) {
  int t = blockIdx.x * blockDim.x + threadIdx.x;
  if (t >= 2 * HWPX) return;
  int b = t / HWPX, p = t - b * HWPX;
  const float* src = emb + (size_t)b * CC * HWPX + p;
  float* dst = eT + (size_t)t * CC;
  __half* dsth = eTh + (size_t)t * CC;
  float acc = 0.f;
  #pragma unroll 4
  for (int c = 0; c < CC; c += 4) {
    float v0 = src[(size_t)(c + 0) * HWPX];
    float v1 = src[(size_t)(c + 1) * HWPX];
    float v2 = src[(size_t)(c + 2) * HWPX];
    float v3 = src[(size_t)(c + 3) * HWPX];
    acc += v0*v0 + v1*v1 + v2*v2 + v3*v3;
    *reinterpret_cast<float4*>(dst + c) = make_float4(v0, v1, v2, v3);
    uint2 hp;
    hp.x = pack2h(v0, v1);
    hp.y = pack2h(v2, v3);
    *reinterpret_cast<uint2*>(dsth + c) = hp;   // 8B aligned (c%4==0)
  }
  e2[t] = acc;
}

// ---------------- Kernel B: one streaming pass over memory bank --------------
// 8 lanes per pixel, 8 pixels per wave; no divergence; reductions at end.
__global__ __launch_bounds__(256) void kpass1(const float* __restrict__ mb,
                       const float* __restrict__ eT,
                       float* __restrict__ mrow2, float* __restrict__ dotacc,
                       float* __restrict__ m2acc) {
  int n = blockIdx.x / 98, chunk = blockIdx.x % 98;
  int wave = threadIdx.x >> 6, lane = threadIdx.x & 63;
  int sub = lane >> 3;          // pixel within wave's 8
  int cl  = lane & 7;           // float4-lane within pixel row
  int p = chunk * 32 + wave * 8 + sub;
  const float4* mr  = reinterpret_cast<const float4*>(mb) + ((size_t)n * HWPX + p) * 112;
  const float4* er0 = reinterpret_cast<const float4*>(eT) + (size_t)p * 112;
  const float4* er1 = er0 + (size_t)HWPX * 112;
  float m2 = 0.f, d0 = 0.f, d1 = 0.f;
  #pragma unroll
  for (int it = 0; it < 14; ++it) {
    int f = cl + it * 8;        // 0..111
    float4 m = mr[f], a = er0[f], b2 = er1[f];
    m2 += dot4(m, m); d0 += dot4(m, a); d1 += dot4(m, b2);
  }
  // per-pixel m2 over the 8 lanes of its group
  m2 += __shfl_xor(m2, 1); m2 += __shfl_xor(m2, 2); m2 += __shfl_xor(m2, 4);
  if (cl == 0) mrow2[(size_t)n * HWPX + p] = m2;
  // wave total m2 (sum of 8 group-sums; tree over group bits)
  m2 += __shfl_xor(m2, 8); m2 += __shfl_xor(m2, 16); m2 += __shfl_xor(m2, 32);
  #pragma unroll
  for (int s = 1; s < 64; s <<= 1) { d0 += __shfl_xor(d0, s); d1 += __shfl_xor(d1, s); }
  if (lane == 0) {
    atomicAdd(&dotacc[n], d0);
    atomicAdd(&dotacc[NBANK + n], d1);
    atomicAdd(&m2acc[n], m2);
  }
}

// ---------------- Kernel C: dist, top-20 (min), pred_score, gaussian weights --
__global__ void kselect(const float* __restrict__ m2acc, const float* __restrict__ e2,
                        const float* __restrict__ dotacc, int* __restrict__ topidx,
                        float* __restrict__ gw, float* __restrict__ pred) {
  __shared__ float s_m2[NBANK];
  __shared__ float s_e2t[2];
  int wave = threadIdx.x >> 6, lane = threadIdx.x & 63;
  if (threadIdx.x < NBANK) s_m2[threadIdx.x] = m2acc[threadIdx.x];
  if (wave < 2) {
    float s = 0.f;
    for (int i = lane; i < HWPX; i += 64) s += e2[wave * HWPX + i];
    #pragma unroll
    for (int m = 1; m < 64; m <<= 1) s += __shfl_xor(s, m);
    if (lane == 0) s_e2t[wave] = s;
  }
  __syncthreads();
  if (threadIdx.x == 0) {
    float wsum = 0.f, wv[33];
    for (int t = 0; t < 33; ++t) {
      float x = (t - 16) * 0.25f;            // (t-R)/SIGMA
      wv[t] = expf(-0.5f * x * x);
      wsum += wv[t];
    }
    for (int t = 0; t < 33; ++t) gw[t] = wv[t] / wsum;
  }
  if (wave < 2) {
    int b = wave;
    float e2t = s_e2t[b];
    float va = 1e30f, vb = 1e30f;
    if (lane < NBANK) {
      float d2 = e2t + s_m2[lane] - 2.f * dotacc[b * NBANK + lane];
      va = sqrtf(fmaxf(d2, 0.f));
    }
    if (lane + 64 < NBANK) {
      float d2 = e2t + s_m2[lane + 64] - 2.f * dotacc[b * NBANK + lane + 64];
      vb = sqrtf(fmaxf(d2, 0.f));
    }
    float sum = 0.f;
    for (int k = 0; k < KIM; ++k) {
      float v = va; int id = lane;
      if (vb < v) { v = vb; id = lane + 64; }
      #pragma unroll
      for (int m = 1; m < 64; m <<= 1) {
        float ov = __shfl_xor(v, m);
        int  oid = __shfl_xor(id, m);
        if (ov < v || (ov == v && oid < id)) { v = ov; id = oid; }
      }
      sum += v;
      if (lane == 0) topidx[b * KIM + k] = id;
      if (id < 64) { if (lane == id) va = 1e30f; }
      else         { if (lane == id - 64) vb = 1e30f; }
    }
    if (lane == 0) pred[b] = sum * (1.f / KIM);
  }
}

// ---------------- Kernel D: windowed NN re-rank (fp16 LDS) -------------------
// XCD-chunked swizzle: each XCD owns a contiguous (k,h) run -> h-overlap is
// L2-local. 5 waves = dy; lanes = w. m/e staged as fp16, swizzled for b128.
__global__ __launch_bounds__(320, 4) void kwin(const float* __restrict__ mb,
                     const __half* __restrict__ eTh, const float* __restrict__ mrow2,
                     const float* __restrict__ e2, const int* __restrict__ topidx,
                     float* __restrict__ best) {
  // bijective XCD swizzle (2240 % 8 == 0)
  int bid = blockIdx.x;
  int L = (bid & 7) * (2 * KIM * HH / 8) + (bid >> 3);
  int h = L % HH;
  int k = (L / HH) % KIM;
  int b = L / (HH * KIM);
  int n = topidx[b * KIM + k];
  int dy = threadIdx.x >> 6;       // 0..4
  int lane = threadIdx.x & 63;     // w when < 56
  int hp = h + dy - 2;
  bool rowok = (hp >= 0) && (hp < HH);
  __shared__ __align__(16) __half lds_m[300 * CCH];   // 19200 B
  __shared__ __align__(16) __half lds_e[WW * CCH];    //  3584 B
  __shared__ unsigned s_best[WW];
  if (threadIdx.x < WW) s_best[threadIdx.x] = 0x7f7f7f7fu;
  const float4* m4 = reinterpret_cast<const float4*>(mb + (size_t)n * HWPX * CC);
  const __half* erow = eTh + ((size_t)b * HWPX + h * WW) * CC;
  int dy60 = dy * 60;
  float acc[5] = {0.f, 0.f, 0.f, 0.f, 0.f};
  for (int c0 = 0; c0 < CC; c0 += CCH) {
    int c0f = c0 >> 2;   // float4 offset
    // ---- stage m: 300 rows x 32 ch; thread -> (row r, quad q of 4 ch) ----
    #pragma unroll
    for (int it = 0; it < 8; ++it) {
      int idx = threadIdx.x + it * 320;
      if (idx < 2400) {
        int r = idx >> 3, q = idx & 7;
        int hh2 = r / 60;
        int wp = r - hh2 * 60;
        int h2 = h + hh2 - 2;
        int w2 = wp - 2;
        float4 v = make_float4(0.f, 0.f, 0.f, 0.f);
        if (h2 >= 0 && h2 < HH && w2 >= 0 && w2 < WW)
          v = m4[(size_t)(h2 * WW + w2) * 112 + c0f + q];
        uint2 hv;
        hv.x = pack2h(v.x, v.y);
        hv.y = pack2h(v.z, v.w);
        int j2 = (q >> 1) ^ ((r >> 1) & 3);
        *reinterpret_cast<uint2*>(&lds_m[r * CCH + j2 * 8 + (q & 1) * 4]) = hv;
      }
    }
    // ---- stage e: 56 rows x 32 ch; thread -> (row er, 16B slot eq) ----
    if (threadIdx.x < 224) {
      int er = threadIdx.x >> 2, eq = threadIdx.x & 3;
      uint4 v = *reinterpret_cast<const uint4*>(erow + (size_t)er * CC + c0 + eq * 8);
      int j2 = eq ^ ((er >> 1) & 3);
      *reinterpret_cast<uint4*>(&lds_e[er * CCH + j2 * 8]) = v;
    }
    __syncthreads();
    // ---- compute ----
    if (lane < WW) {
      #pragma unroll
      for (int j = 0; j < 4; ++j) {
        uint4 eu = *reinterpret_cast<const uint4*>(
            &lds_e[lane * CCH + ((j ^ ((lane >> 1) & 3)) << 3)]);
        float2 ea = __half22float2(*reinterpret_cast<const __half2*>(&eu.x));
        float2 eb = __half22float2(*reinterpret_cast<const __half2*>(&eu.y));
        float2 ec = __half22float2(*reinterpret_cast<const __half2*>(&eu.z));
        float2 ed = __half22float2(*reinterpret_cast<const __half2*>(&eu.w));
        #pragma unroll
        for (int dx = 0; dx < 5; ++dx) {
          int r = dy60 + lane + dx;
          uint4 mu = *reinterpret_cast<const uint4*>(
              &lds_m[r * CCH + ((j ^ ((r >> 1) & 3)) << 3)]);
          float2 ma = __half22float2(*reinterpret_cast<const __half2*>(&mu.x));
          float2 mb2 = __half22float2(*reinterpret_cast<const __half2*>(&mu.y));
          float2 mc = __half22float2(*reinterpret_cast<const __half2*>(&mu.z));
          float2 md = __half22float2(*reinterpret_cast<const __half2*>(&mu.w));
          acc[dx] += ea.x*ma.x + ea.y*ma.y + eb.x*mb2.x + eb.y*mb2.y
                   + ec.x*mc.x + ec.y*mc.y + ed.x*md.x + ed.y*md.y;
        }
      }
    }
    __syncthreads();
  }
  if (rowok && lane < WW) {
    float e2v = e2[b * HWPX + h * WW + lane];
    float lbest = 1e30f;
    #pragma unroll
    for (int dx = 0; dx < 5; ++dx) {
      int w2 = lane + dx - 2;
      if (w2 >= 0 && w2 < WW) {
        float m2v = mrow2[(size_t)n * HWPX + hp * WW + w2];
        float d2w = fmaxf(e2v + m2v - 2.f * acc[dx], 0.f);
        lbest = fminf(lbest, d2w);
      }
    }
    if (lbest < 1e30f) atomicMin(&s_best[lane], __float_as_uint(lbest));
  }
  __syncthreads();
  if (threadIdx.x < WW) {
    unsigned v = s_best[threadIdx.x];
    if (v != 0x7f7f7f7fu)
      atomicMin(reinterpret_cast<unsigned*>(&best[b * HWPX + h * WW + threadIdx.x]), v);
  }
}

// ---------------- Kernel E1: sqrt + bilinear 56 -> 224 -----------------------
__global__ void kresize(const float* __restrict__ best, float* __restrict__ rsz) {
  int t = blockIdx.x * blockDim.x + threadIdx.x;
  if (t >= 2 * OUTHW * OUTHW) return;
  int b = t / (OUTHW * OUTHW), r = t - b * OUTHW * OUTHW;
  int oy = r / OUTHW, ox = r - oy * OUTHW;
  float ys = (oy + 0.5f) * 0.25f - 0.5f;
  float xs = (ox + 0.5f) * 0.25f - 0.5f;
  float yf = floorf(ys), xf = floorf(xs);
  float fy = ys - yf, fx = xs - xf;
  int y0 = (int)yf, x0 = (int)xf;
  int y0c = y0 < 0 ? 0 : y0;        int y1c = y0 + 1 > 55 ? 55 : (y0 + 1 < 0 ? 0 : y0 + 1);
  int x0c = x0 < 0 ? 0 : x0;        int x1c = x0 + 1 > 55 ? 55 : (x0 + 1 < 0 ? 0 : x0 + 1);
  const float* bb = best + b * HWPX;
  float v00 = sqrtf(bb[y0c * WW + x0c]);
  float v01 = sqrtf(bb[y0c * WW + x1c]);
  float v10 = sqrtf(bb[y1c * WW + x0c]);
  float v11 = sqrtf(bb[y1c * WW + x1c]);
  float v0 = v00 + (v01 - v00) * fx;
  float v1 = v10 + (v11 - v10) * fx;
  rsz[t] = v0 + (v1 - v0) * fy;
}

// ---------------- Kernel E2/E3: separable Gaussian blur (reflect) ------------
__global__ void kblurv(const float* __restrict__ in, const float* __restrict__ gw,
                       float* __restrict__ o) {
  int t = blockIdx.x * blockDim.x + threadIdx.x;
  if (t >= 2 * OUTHW * OUTHW) return;
  int b = t / (OUTHW * OUTHW), r = t - b * OUTHW * OUTHW;
  int y = r / OUTHW, x = r - y * OUTHW;
  float s = 0.f;
  #pragma unroll
  for (int u = -16; u <= 16; ++u) {
    int yy = y + u;
    yy = yy < 0 ? -yy : (yy > 223 ? 446 - yy : yy);
    s += gw[u + 16] * in[b * OUTHW * OUTHW + yy * OUTHW + x];
  }
  o[t] = s;
}

__global__ void kblurh(const float* __restrict__ in, const float* __restrict__ gw,
                       float* __restrict__ o) {
  int t = blockIdx.x * blockDim.x + threadIdx.x;
  if (t >= 2 * OUTHW * OUTHW) return;
  int b = t / (OUTHW * OUTHW), r = t - b * OUTHW * OUTHW;
  int y = r / OUTHW, x = r - y * OUTHW;
  float s = 0.f;
  #pragma unroll
  for (int u = -16; u <= 16; ++u) {
    int xx = x + u;
    xx = xx < 0 ? -xx : (xx > 223 ? 446 - xx : xx);
    s += gw[u + 16] * in[b * OUTHW * OUTHW + y * OUTHW + xx];
  }
  o[t] = s;
}

// ---------------- launch -----------------------------------------------------
extern "C" void kernel_launch(void* const* d_in, const int* in_sizes, int n_in,
                              void* d_out, int out_size, void* d_ws, size_t ws_size,
                              hipStream_t stream) {
  const float* emb   = (const float*)d_in[0];
  const float* mbank = (const float*)d_in[1];
  float* out = (float*)d_out;
  float* ws  = (float*)d_ws;

  size_t off = 0;
  float* eT     = ws + off; off += (size_t)2 * HWPX * CC;   // 2,809,856
  float* e2     = ws + off; off += 2 * HWPX;                // 6,272
  float* mrow2  = ws + off; off += (size_t)NBANK * HWPX;    // 313,600
  float* dotacc = ws + off; off += 2 * NBANK;               // 200  (zeroed)
  float* m2acc  = ws + off; off += NBANK;                   // 100  (zeroed)
  int*   topidx = (int*)(ws + off); off += 2 * KIM;         // 40
  float* gw     = ws + off; off += 34;                      // 33 + pad
  float* best   = ws + off; off += 2 * HWPX;                // 6,272 (memset 0x7f)
  float* rsz    = ws + off; off += (size_t)2 * OUTHW * OUTHW;
  float* tmp    = ws + off; off += (size_t)2 * OUTHW * OUTHW;
  __half* eTh   = (__half*)(ws + off); off += (size_t)2 * HWPX * CC / 2;  // fp16 copy
  // total ~19 MB of workspace

  hipMemsetAsync(dotacc, 0, (2 * NBANK + NBANK) * sizeof(float), stream);
  hipMemsetAsync(best, 0x7f, 2 * HWPX * sizeof(float), stream);  // 0x7f7f7f7f ~ 3.4e38

  hipLaunchKernelGGL(ktrans, dim3((2 * HWPX + 255) / 256), dim3(256), 0, stream,
                     emb, eT, eTh, e2);
  hipLaunchKernelGGL(kpass1, dim3(NBANK * 98), dim3(256), 0, stream,
                     mbank, eT, mrow2, dotacc, m2acc);
  hipLaunchKernelGGL(kselect, dim3(1), dim3(256), 0, stream,
                     m2acc, e2, dotacc, topidx, gw, out);
  hipLaunchKernelGGL(kwin, dim3(2 * HH * KIM), dim3(320), 0, stream,
                     mbank, eTh, mrow2, e2, topidx, best);
  int npix = 2 * OUTHW * OUTHW;
  hipLaunchKernelGGL(kresize, dim3((npix + 255) / 256), dim3(256), 0, stream, best, rsz);
  hipLaunchKernelGGL(kblurv, dim3((npix + 255) / 256), dim3(256), 0, stream, rsz, gw, tmp);
  hipLaunchKernelGGL(kblurh, dim3((npix + 255) / 256), dim3(256), 0, stream, tmp, gw, out + 2);
}

// Round 7
// 977.954 us; speedup vs baseline: 2.5165x; 2.5165x over previous
//
#include <hip/hip_runtime.h>
#include <hip/hip_fp16.h>
#include <math.h>

#define HH 56
#define WW 56
#define HWPX 3136        // 56*56
#define CC 448
#define NBANK 100
#define KIM 20
#define OUTHW 224
#define CCH 32           // channels per chunk in kwin (fp16 LDS)

__device__ __forceinline__ float dot4(float4 a, float4 b) {
  return a.x*b.x + a.y*b.y + a.z*b.z + a.w*b.w;
}

__device__ __forceinline__ unsigned pack2h(float a, float b) {
  __half2 h;
  h.x = __float2half_rn(a);
  h.y = __float2half_rn(b);
  return *reinterpret_cast<unsigned*>(&h);
}

typedef _Float16 half2v __attribute__((ext_vector_type(2)));

// 2-way fp16 dot with f32 accumulate (v_dot2_f32_f16); guarded fallback.
__device__ __forceinline__ float fdot2(unsigned a, unsigned b, float c) {
#if __has_builtin(__builtin_amdgcn_fdot2)
  return __builtin_amdgcn_fdot2(*reinterpret_cast<half2v*>(&a),
                                *reinterpret_cast<half2v*>(&b), c, false);
#else
  float2 fa = __half22float2(*reinterpret_cast<__half2*>(&a));
  float2 fb = __half22float2(*reinterpret_cast<__half2*>(&b));
  return c + fa.x*fb.x + fa.y*fb.y;
#endif
}

// ---------------- Kernel A: tiled transpose (B,C,H,W)->(B,HW,C) + e2 ---------
// grid 2 x 7 x 49 = 686 blocks, 256 thr. Coalesced loads along p, stores along c.
__global__ void ktrans(const float* __restrict__ emb, float* __restrict__ eT,
                       __half* __restrict__ eTh, float* __restrict__ e2) {
  int bid = blockIdx.x;
  int pt = bid % 49, ct = (bid / 49) % 7, b = bid / (49 * 7);
  __shared__ float tile[64][65];
  __shared__ float s_e2[64];
  int tx = threadIdx.x & 63, ty = threadIdx.x >> 6;   // ty 0..3
  if (threadIdx.x < 64) s_e2[threadIdx.x] = 0.f;
  __syncthreads();
  const float* src = emb + ((size_t)b * CC + ct * 64) * HWPX + pt * 64;
  float psum = 0.f;
  #pragma unroll
  for (int i = 0; i < 16; ++i) {
    int c = ty * 16 + i;
    float v = src[(size_t)c * HWPX + tx];
    tile[c][tx] = v;
    psum += v * v;
  }
  atomicAdd(&s_e2[tx], psum);          // LDS atomic, 4-way
  __syncthreads();
  if (threadIdx.x < 64)
    atomicAdd(&e2[(size_t)b * HWPX + pt * 64 + threadIdx.x], s_e2[threadIdx.x]);
  #pragma unroll
  for (int i = 0; i < 16; ++i) {
    int p = ty * 16 + i;
    float v = tile[tx][p];
    size_t gp = (size_t)b * HWPX + pt * 64 + p;
    eT[gp * CC + ct * 64 + tx] = v;
    eTh[gp * CC + ct * 64 + tx] = __float2half_rn(v);
  }
}

// ---------------- Kernel B: streaming pass over memory bank ------------------
// 8 lanes/pixel, 8 pixels/wave; batched load groups; NO global atomics:
// per-block partials -> pd0/pd1/pm2 (reduced in kselect).
__global__ __launch_bounds__(256) void kpass1(const float* __restrict__ mb,
                       const float* __restrict__ eT,
                       float* __restrict__ mrow2, float* __restrict__ pd0,
                       float* __restrict__ pd1, float* __restrict__ pm2) {
  int n = blockIdx.x / 98, chunk = blockIdx.x % 98;
  int wave = threadIdx.x >> 6, lane = threadIdx.x & 63;
  int sub = lane >> 3;          // pixel within wave's 8
  int cl  = lane & 7;           // float4-lane within pixel row
  int p = chunk * 32 + wave * 8 + sub;
  const float4* mr  = reinterpret_cast<const float4*>(mb) + ((size_t)n * HWPX + p) * 112;
  const float4* er0 = reinterpret_cast<const float4*>(eT) + (size_t)p * 112;
  const float4* er1 = er0 + (size_t)HWPX * 112;
  float m2 = 0.f, d0 = 0.f, d1 = 0.f;
  #pragma unroll
  for (int g = 0; g < 14; g += 7) {
    float4 vm[7], va[7], vb[7];
    #pragma unroll
    for (int i = 0; i < 7; ++i) {
      int f = cl + (g + i) * 8;
      vm[i] = mr[f]; va[i] = er0[f]; vb[i] = er1[f];
    }
    #pragma unroll
    for (int i = 0; i < 7; ++i) {
      m2 += dot4(vm[i], vm[i]); d0 += dot4(vm[i], va[i]); d1 += dot4(vm[i], vb[i]);
    }
  }
  // per-pixel m2 over the 8 lanes of its group
  m2 += __shfl_xor(m2, 1); m2 += __shfl_xor(m2, 2); m2 += __shfl_xor(m2, 4);
  if (cl == 0) mrow2[(size_t)n * HWPX + p] = m2;
  // wave totals
  m2 += __shfl_xor(m2, 8); m2 += __shfl_xor(m2, 16); m2 += __shfl_xor(m2, 32);
  #pragma unroll
  for (int s = 1; s < 64; s <<= 1) { d0 += __shfl_xor(d0, s); d1 += __shfl_xor(d1, s); }
  __shared__ float s_red[4][3];
  if (lane == 0) { s_red[wave][0] = d0; s_red[wave][1] = d1; s_red[wave][2] = m2; }
  __syncthreads();
  if (threadIdx.x == 0) {
    float t0 = s_red[0][0] + s_red[1][0] + s_red[2][0] + s_red[3][0];
    float t1 = s_red[0][1] + s_red[1][1] + s_red[2][1] + s_red[3][1];
    float t2 = s_red[0][2] + s_red[1][2] + s_red[2][2] + s_red[3][2];
    pd0[chunk * NBANK + n] = t0;
    pd1[chunk * NBANK + n] = t1;
    pm2[chunk * NBANK + n] = t2;
  }
}

// ---------------- Kernel C: reduce partials, dist, top-20, pred, gaussian ----
__global__ void kselect(const float* __restrict__ pd0, const float* __restrict__ pd1,
                        const float* __restrict__ pm2, const float* __restrict__ e2,
                        int* __restrict__ topidx, float* __restrict__ gw,
                        float* __restrict__ pred) {
  __shared__ float s_m2[NBANK], s_d0[NBANK], s_d1[NBANK];
  __shared__ float s_e2t[2];
  int wave = threadIdx.x >> 6, lane = threadIdx.x & 63;
  if (threadIdx.x < NBANK) {
    float a0 = 0.f, a1 = 0.f, a2 = 0.f;
    for (int ch = 0; ch < 98; ++ch) {
      a0 += pd0[ch * NBANK + threadIdx.x];
      a1 += pd1[ch * NBANK + threadIdx.x];
      a2 += pm2[ch * NBANK + threadIdx.x];
    }
    s_d0[threadIdx.x] = a0; s_d1[threadIdx.x] = a1; s_m2[threadIdx.x] = a2;
  }
  if (wave == 2) {
    float s = 0.f;
    for (int i = lane; i < HWPX; i += 64) s += e2[i];
    #pragma unroll
    for (int m = 1; m < 64; m <<= 1) s += __shfl_xor(s, m);
    if (lane == 0) s_e2t[0] = s;
  }
  if (wave == 3) {
    float s = 0.f;
    for (int i = lane; i < HWPX; i += 64) s += e2[HWPX + i];
    #pragma unroll
    for (int m = 1; m < 64; m <<= 1) s += __shfl_xor(s, m);
    if (lane == 0) s_e2t[1] = s;
  }
  if (threadIdx.x == 0) {
    float wsum = 0.f, wv[33];
    for (int t = 0; t < 33; ++t) {
      float x = (t - 16) * 0.25f;            // (t-R)/SIGMA
      wv[t] = expf(-0.5f * x * x);
      wsum += wv[t];
    }
    for (int t = 0; t < 33; ++t) gw[t] = wv[t] / wsum;
  }
  __syncthreads();
  if (wave < 2) {
    int b = wave;
    float e2t = s_e2t[b];
    float va = 1e30f, vb = 1e30f;
    if (lane < NBANK) {
      float dd = (b == 0) ? s_d0[lane] : s_d1[lane];
      float d2 = e2t + s_m2[lane] - 2.f * dd;
      va = sqrtf(fmaxf(d2, 0.f));
    }
    if (lane + 64 < NBANK) {
      float dd = (b == 0) ? s_d0[lane + 64] : s_d1[lane + 64];
      float d2 = e2t + s_m2[lane + 64] - 2.f * dd;
      vb = sqrtf(fmaxf(d2, 0.f));
    }
    float sum = 0.f;
    for (int k = 0; k < KIM; ++k) {
      float v = va; int id = lane;
      if (vb < v) { v = vb; id = lane + 64; }
      #pragma unroll
      for (int m = 1; m < 64; m <<= 1) {
        float ov = __shfl_xor(v, m);
        int  oid = __shfl_xor(id, m);
        if (ov < v || (ov == v && oid < id)) { v = ov; id = oid; }
      }
      sum += v;
      if (lane == 0) topidx[b * KIM + k] = id;
      if (id < 64) { if (lane == id) va = 1e30f; }
      else         { if (lane == id - 64) vb = 1e30f; }
    }
    if (lane == 0) pred[b] = sum * (1.f / KIM);
  }
}

// ---------------- Kernel D: windowed NN re-rank (fp16 LDS, prefetch) ---------
// XCD-chunked bijective swizzle; 5 waves = dy; lanes = w.
// Register prefetch of chunk c+1 issued before compute of chunk c (T14).
// No global atomics: per-(b,k) results to best_k, min-reduced in kminred.
__global__ __launch_bounds__(320) void kwin(const float* __restrict__ mb,
                     const __half* __restrict__ eTh, const float* __restrict__ mrow2,
                     const float* __restrict__ e2, const int* __restrict__ topidx,
                     float* __restrict__ best_k) {
  int bid = blockIdx.x;
  int L = (bid & 7) * 280 + (bid >> 3);   // 2240 % 8 == 0, bijective
  int h = L % HH;
  int k = (L / HH) % KIM;
  int b = L / (HH * KIM);
  int n = topidx[b * KIM + k];
  int dy = threadIdx.x >> 6;       // 0..4
  int lane = threadIdx.x & 63;     // w when < 56
  int hp = h + dy - 2;
  bool rowok = (hp >= 0) && (hp < HH);
  __shared__ __align__(16) __half lds_m[300 * CCH];   // 19200 B
  __shared__ __align__(16) __half lds_e[WW * CCH];    //  3584 B
  __shared__ unsigned s_best[WW];
  if (threadIdx.x < WW) s_best[threadIdx.x] = 0x7f7f7f7fu;
  const float4* m4 = reinterpret_cast<const float4*>(mb + (size_t)n * HWPX * CC);
  const __half* erow = eTh + ((size_t)b * HWPX + h * WW) * CC;

  // per-thread staging descriptors (chunk-invariant)
  int gidx[8], lofs[8];
  #pragma unroll
  for (int it = 0; it < 8; ++it) {
    int idx = threadIdx.x + it * 320;
    int r = idx >> 3, q = idx & 7;
    int hh2 = r / 60, wp = r - hh2 * 60;
    int h2 = h + hh2 - 2, w2 = wp - 2;
    bool inb = idx < 2400;
    bool valid = inb && h2 >= 0 && h2 < HH && w2 >= 0 && w2 < WW;
    gidx[it] = valid ? ((h2 * WW + w2) * 112 + q) : -1;
    lofs[it] = inb ? (r * CCH + (((q >> 1) ^ ((r >> 1) & 3)) << 3) + ((q & 1) << 2)) : -1;
  }
  bool edo = threadIdx.x < 224;
  int er = threadIdx.x >> 2, eq = threadIdx.x & 3;
  int geofs = er * CC + eq * 8;
  int leofs = er * CCH + ((eq ^ ((er >> 1) & 3)) << 3);

  // prologue: prefetch chunk 0 into registers
  float4 pm[8]; uint4 pe;
  #pragma unroll
  for (int it = 0; it < 8; ++it)
    pm[it] = (gidx[it] >= 0) ? m4[gidx[it]] : make_float4(0.f, 0.f, 0.f, 0.f);
  if (edo) pe = *reinterpret_cast<const uint4*>(erow + geofs);

  int dy60 = dy * 60;
  float acc[5] = {0.f, 0.f, 0.f, 0.f, 0.f};
  for (int c = 0; c < 14; ++c) {
    // write staged registers to LDS (compiler inserts vmcnt wait here)
    #pragma unroll
    for (int it = 0; it < 8; ++it) {
      if (lofs[it] >= 0) {
        uint2 hv;
        hv.x = pack2h(pm[it].x, pm[it].y);
        hv.y = pack2h(pm[it].z, pm[it].w);
        *reinterpret_cast<uint2*>(&lds_m[lofs[it]]) = hv;
      }
    }
    if (edo) *reinterpret_cast<uint4*>(&lds_e[leofs]) = pe;
    __syncthreads();
    // prefetch chunk c+1 (in flight during compute below)
    if (c < 13) {
      int c0f = (c + 1) * (CCH / 4);
      #pragma unroll
      for (int it = 0; it < 8; ++it)
        pm[it] = (gidx[it] >= 0) ? m4[gidx[it] + c0f] : make_float4(0.f, 0.f, 0.f, 0.f);
      if (edo) pe = *reinterpret_cast<const uint4*>(erow + geofs + (c + 1) * CCH);
    }
    // compute chunk c from LDS
    if (lane < WW) {
      #pragma unroll
      for (int j = 0; j < 4; ++j) {
        uint4 eu = *reinterpret_cast<const uint4*>(
            &lds_e[lane * CCH + ((j ^ ((lane >> 1) & 3)) << 3)]);
        #pragma unroll
        for (int dx = 0; dx < 5; ++dx) {
          int r = dy60 + lane + dx;
          uint4 mu = *reinterpret_cast<const uint4*>(
              &lds_m[r * CCH + ((j ^ ((r >> 1) & 3)) << 3)]);
          acc[dx] = fdot2(eu.x, mu.x,
                    fdot2(eu.y, mu.y,
                    fdot2(eu.z, mu.z,
                    fdot2(eu.w, mu.w, acc[dx]))));
        }
      }
    }
    __syncthreads();
  }
  if (rowok && lane < WW) {
    float e2v = e2[b * HWPX + h * WW + lane];
    float lbest = 1e30f;
    #pragma unroll
    for (int dx = 0; dx < 5; ++dx) {
      int w2 = lane + dx - 2;
      if (w2 >= 0 && w2 < WW) {
        float m2v = mrow2[(size_t)n * HWPX + hp * WW + w2];
        float d2w = fmaxf(e2v + m2v - 2.f * acc[dx], 0.f);
        lbest = fminf(lbest, d2w);
      }
    }
    atomicMin(&s_best[lane], __float_as_uint(lbest));   // LDS atomic only
  }
  __syncthreads();
  if (threadIdx.x < WW)
    best_k[((size_t)(b * KIM + k)) * HWPX + h * WW + threadIdx.x] =
        __uint_as_float(s_best[threadIdx.x]);
}

// ---------------- Kernel D2: min over k + sqrt -> patch ----------------------
__global__ void kminred(const float* __restrict__ best_k, float* __restrict__ patch) {
  int t = blockIdx.x * blockDim.x + threadIdx.x;
  if (t >= 2 * HWPX) return;
  int b = t / HWPX, p = t - b * HWPX;
  float m = 1e30f;
  #pragma unroll 4
  for (int k = 0; k < KIM; ++k)
    m = fminf(m, best_k[((size_t)(b * KIM + k)) * HWPX + p]);
  patch[t] = sqrtf(m);
}

// ---------------- Kernel E1: bilinear 56 -> 224 ------------------------------
__global__ void kresize(const float* __restrict__ patch, float* __restrict__ rsz) {
  int t = blockIdx.x * blockDim.x + threadIdx.x;
  if (t >= 2 * OUTHW * OUTHW) return;
  int b = t / (OUTHW * OUTHW), r = t - b * OUTHW * OUTHW;
  int oy = r / OUTHW, ox = r - oy * OUTHW;
  float ys = (oy + 0.5f) * 0.25f - 0.5f;
  float xs = (ox + 0.5f) * 0.25f - 0.5f;
  float yf = floorf(ys), xf = floorf(xs);
  float fy = ys - yf, fx = xs - xf;
  int y0 = (int)yf, x0 = (int)xf;
  int y0c = y0 < 0 ? 0 : y0;        int y1c = y0 + 1 > 55 ? 55 : (y0 + 1 < 0 ? 0 : y0 + 1);
  int x0c = x0 < 0 ? 0 : x0;        int x1c = x0 + 1 > 55 ? 55 : (x0 + 1 < 0 ? 0 : x0 + 1);
  const float* bb = patch + b * HWPX;
  float v00 = bb[y0c * WW + x0c];
  float v01 = bb[y0c * WW + x1c];
  float v10 = bb[y1c * WW + x0c];
  float v11 = bb[y1c * WW + x1c];
  float v0 = v00 + (v01 - v00) * fx;
  float v1 = v10 + (v11 - v10) * fx;
  rsz[t] = v0 + (v1 - v0) * fy;
}

// ---------------- Kernel E2/E3: separable Gaussian blur (reflect) ------------
__global__ void kblurv(const float* __restrict__ in, const float* __restrict__ gw,
                       float* __restrict__ o) {
  int t = blockIdx.x * blockDim.x + threadIdx.x;
  if (t >= 2 * OUTHW * OUTHW) return;
  int b = t / (OUTHW * OUTHW), r = t - b * OUTHW * OUTHW;
  int y = r / OUTHW, x = r - y * OUTHW;
  float s = 0.f;
  #pragma unroll
  for (int u = -16; u <= 16; ++u) {
    int yy = y + u;
    yy = yy < 0 ? -yy : (yy > 223 ? 446 - yy : yy);
    s += gw[u + 16] * in[b * OUTHW * OUTHW + yy * OUTHW + x];
  }
  o[t] = s;
}

__global__ void kblurh(const float* __restrict__ in, const float* __restrict__ gw,
                       float* __restrict__ o) {
  int t = blockIdx.x * blockDim.x + threadIdx.x;
  if (t >= 2 * OUTHW * OUTHW) return;
  int b = t / (OUTHW * OUTHW), r = t - b * OUTHW * OUTHW;
  int y = r / OUTHW, x = r - y * OUTHW;
  float s = 0.f;
  #pragma unroll
  for (int u = -16; u <= 16; ++u) {
    int xx = x + u;
    xx = xx < 0 ? -xx : (xx > 223 ? 446 - xx : xx);
    s += gw[u + 16] * in[b * OUTHW * OUTHW + y * OUTHW + xx];
  }
  o[t] = s;
}

// ---------------- launch -----------------------------------------------------
extern "C" void kernel_launch(void* const* d_in, const int* in_sizes, int n_in,
                              void* d_out, int out_size, void* d_ws, size_t ws_size,
                              hipStream_t stream) {
  const float* emb   = (const float*)d_in[0];
  const float* mbank = (const float*)d_in[1];
  float* out = (float*)d_out;
  float* ws  = (float*)d_ws;

  // all segment sizes are multiples of 8 floats -> every pointer 16B-aligned
  size_t off = 0;
  float* eT     = ws + off; off += (size_t)2 * HWPX * CC;   // 2,809,856
  float* e2     = ws + off; off += 2 * HWPX;                // 6,272 (zeroed)
  float* mrow2  = ws + off; off += (size_t)NBANK * HWPX;    // 313,600
  float* pd0    = ws + off; off += 98 * NBANK;              // 9,800
  float* pd1    = ws + off; off += 98 * NBANK;              // 9,800
  float* pm2    = ws + off; off += 98 * NBANK;              // 9,800
  int*   topidx = (int*)(ws + off); off += 2 * KIM;         // 40
  float* gw     = ws + off; off += 40;                      // 33 + pad
  float* best_k = ws + off; off += (size_t)2 * KIM * HWPX;  // 125,440
  float* patch  = ws + off; off += 2 * HWPX;                // 6,272
  float* rsz    = ws + off; off += (size_t)2 * OUTHW * OUTHW;
  float* tmp    = ws + off; off += (size_t)2 * OUTHW * OUTHW;
  __half* eTh   = (__half*)(ws + off); off += (size_t)2 * HWPX * CC / 2;
  // total ~20 MB of workspace

  hipMemsetAsync(e2, 0, 2 * HWPX * sizeof(float), stream);

  hipLaunchKernelGGL(ktrans, dim3(2 * 7 * 49), dim3(256), 0, stream,
                     emb, eT, eTh, e2);
  hipLaunchKernelGGL(kpass1, dim3(NBANK * 98), dim3(256), 0, stream,
                     mbank, eT, mrow2, pd0, pd1, pm2);
  hipLaunchKernelGGL(kselect, dim3(1), dim3(256), 0, stream,
                     pd0, pd1, pm2, e2, topidx, gw, out);
  hipLaunchKernelGGL(kwin, dim3(2 * HH * KIM), dim3(320), 0, stream,
                     mbank, eTh, mrow2, e2, topidx, best_k);
  hipLaunchKernelGGL(kminred, dim3((2 * HWPX + 255) / 256), dim3(256), 0, stream,
                     best_k, patch);
  int npix = 2 * OUTHW * OUTHW;
  hipLaunchKernelGGL(kresize, dim3((npix + 255) / 256), dim3(256), 0, stream, patch, rsz);
  hipLaunchKernelGGL(kblurv, dim3((npix + 255) / 256), dim3(256), 0, stream, rsz, gw, tmp);
  hipLaunchKernelGGL(kblurh, dim3((npix + 255) / 256), dim3(256), 0, stream, tmp, gw, out + 2);
}